// Round 5
// baseline (591.927 us; speedup 1.0000x reference)
//
#include <hip/hip_runtime.h>
#include <stdint.h>

// ---------------------------------------------------------------------------
// Llama GQA attention layer, MI355X/gfx950.
// Pipeline: cast->bf16, QKV gemm (256^2 8-wave, m201-style phase-paired
//           MFMA), RoPE, V-transpose, MFMA flash attention, O-proj gemm 128^2.
// 256^2 GEMM core v5: m201 8-phase template recut onto ring-4 BK=32 slots.
// Per phase: {4-8 ds_read | 2 gload_lds stage | barrier | lgkm0 | setprio(1)
// 16 MFMA setprio(0) | barrier}. Counted vmcnt (8/4/0, never 0 in steady
// state). Conflict-free XOR swizzle f(row)=(row>>1)&3 (verified 0 conflicts).
// ---------------------------------------------------------------------------

typedef __attribute__((ext_vector_type(8))) __bf16 bf16x8;
typedef __attribute__((ext_vector_type(4))) float floatx4;

#define S_LEN 2048
#define HID   4096
#define NH    32
#define NKV   8
#define HD    128

__device__ __forceinline__ unsigned short f2bf(float f) {
  union { float f; uint32_t u; } v; v.f = f;
  return (unsigned short)((v.u + 0x7fffu + ((v.u >> 16) & 1u)) >> 16);
}

__device__ __forceinline__ void gload_lds16(const unsigned short* g, unsigned short* l) {
  __builtin_amdgcn_global_load_lds(
      (const __attribute__((address_space(1))) void*)g,
      (__attribute__((address_space(3))) void*)l,
      16, 0, 0);
}

// ---------------------------------------------------------------------------
__global__ void cast_bf16_kernel(const float* __restrict__ in,
                                 unsigned short* __restrict__ out, int n4) {
  int i = blockIdx.x * blockDim.x + threadIdx.x;
  if (i >= n4) return;
  float4 f = ((const float4*)in)[i];
  ushort4 o = make_ushort4(f2bf(f.x), f2bf(f.y), f2bf(f.z), f2bf(f.w));
  ((ushort4*)out)[i] = o;
}

// ---------------------------------------------------------------------------
// 256x256-tile GEMM v5: C[M,N] (fp32) = A[M,K] (bf16) * B^T, B is [N,K] bf16.
// 512 threads (8 waves = 2M x 4N), wave tile 128x64, BK=32.
// LDS: ring of 4 K-tile slots (A 256x32 + B 256x32 = 32 KB each -> 128 KiB).
// Body t, phase 1: read B frags(4) + A frags mi0-3(4) of slot t, stage A-pair
//   of t+3 -> slot (t-1)&3, barrier, lgkm0, 16 MFMA (acc[0..3]), barrier.
// Body t, phase 2: read A frags mi4-7(4), stage B-pair, barrier, lgkm0,
//   16 MFMA (acc[4..7]), counted vmcnt, barrier.
// Race-freedom: slot s re-staged in body s+... = after its readers' lgkm0
// (each phase's reads complete before that phase's MFMA barrier); stage(t+1)
// retired by vmcnt(8) at end of body t, before body t+1's reads of slot t+1.
// Steady-state outstanding: stages t+1,t+2,t+3 = 12 loads -> vmcnt(8)
// retires stage(t+1). Tail: 8 -> vmcnt(4); 4 -> vmcnt(0).
#define GT 32   // K per tile

__device__ __forceinline__ void read_frag4(
    bf16x8* f, const unsigned short* S, int row0, int l15, int quad) {
#pragma unroll
  for (int i = 0; i < 4; ++i) {
    const int row = row0 + i * 16 + l15;
    f[i] = *(const bf16x8*)&S[row * GT + (((quad ^ (row >> 1)) & 3) * 8)];
  }
}

__device__ __forceinline__ void mfma16(
    const bf16x8* a, const bf16x8* b, floatx4 acc[8][4], int mi0) {
#pragma unroll
  for (int mi = 0; mi < 4; ++mi)
#pragma unroll
    for (int ni = 0; ni < 4; ++ni)
      acc[mi0 + mi][ni] = __builtin_amdgcn_mfma_f32_16x16x32_bf16(
          a[mi], b[ni], acc[mi0 + mi][ni], 0, 0, 0);
}

__global__ __launch_bounds__(512, 2) void gemm_bt256_kernel(
    const unsigned short* __restrict__ A,
    const unsigned short* __restrict__ B,
    float* __restrict__ C, int M, int N, int K) {
  __shared__ unsigned short As[4][256 * GT];   // 64 KB
  __shared__ unsigned short Bs[4][256 * GT];   // 64 KB
  const int m0 = blockIdx.y * 256;
  const int n0 = blockIdx.x * 256;
  const int tid = threadIdx.x;
  const int lane = tid & 63;
  const int wv = tid >> 6;        // 0..7
  const int wr = wv >> 2;         // 0..1 -> rows [wr*128, +128)
  const int wc = wv & 3;          // 0..3 -> cols [wc*64, +64)
  const int l15 = lane & 15;
  const int quad = lane >> 4;

  // staging: thread owns chunks ch0, ch1 (1024 x 16B chunks per operand tile).
  // LDS dest = chunk*16 (linear).  source chunk = ch ^ ((ch>>3)&3)
  // ((ch>>3)&3 == (row>>1)&3 exactly, since chunk-in-row < 4).
  const int ch0 = wv * 64 + lane;
  const int ch1 = ch0 + 512;
  const int cs0 = ch0 ^ ((ch0 >> 3) & 3);
  const int cs1 = ch1 ^ ((ch1 >> 3) & 3);
  const int r0s = cs0 >> 2, c0s = (cs0 & 3) * 8;   // row 0..255, col 0/8/16/24
  const int r1s = cs1 >> 2, c1s = (cs1 & 3) * 8;

  floatx4 acc[8][4];
#pragma unroll
  for (int i = 0; i < 8; i++)
#pragma unroll
    for (int j = 0; j < 4; j++) acc[i][j] = (floatx4){0.f, 0.f, 0.f, 0.f};

  const int T = K / GT;  // assumes K % 32 == 0 && T >= 4 (K=4096 here)

#define STAGE_A(kk0, s)                                                        \
  do {                                                                         \
    gload_lds16(A + (size_t)(m0 + r0s) * K + (kk0) + c0s, &As[s][ch0 * 8]);    \
    gload_lds16(A + (size_t)(m0 + r1s) * K + (kk0) + c1s, &As[s][ch1 * 8]);    \
  } while (0)
#define STAGE_B(kk0, s)                                                        \
  do {                                                                         \
    gload_lds16(B + (size_t)(n0 + r0s) * K + (kk0) + c0s, &Bs[s][ch0 * 8]);    \
    gload_lds16(B + (size_t)(n0 + r1s) * K + (kk0) + c1s, &Bs[s][ch1 * 8]);    \
  } while (0)

  // prologue: stage tiles 0,1,2 (12 loads). vmcnt(8) retires tile 0 before
  // body 0's reads of slot 0.
  STAGE_A(0, 0);      STAGE_B(0, 0);
  STAGE_A(GT, 1);     STAGE_B(GT, 1);
  STAGE_A(2 * GT, 2); STAGE_B(2 * GT, 2);
  asm volatile("s_waitcnt vmcnt(8)" ::: "memory");
  __builtin_amdgcn_s_barrier();

  bf16x8 afr[4], bfr[4];

  for (int t = 0; t < T; ++t) {
    const int s = t & 3;
    const int sn = (t + 3) & 3;
    const bool pf = (t + 3 < T);
    const int kpf = (t + 3) * GT;

    // ---- phase 1: B frags + A frags mi0-3, stage A-pair, 16 MFMA ----
    read_frag4(bfr, Bs[s], wc * 64, l15, quad);
    read_frag4(afr, As[s], wr * 128, l15, quad);
    if (pf) STAGE_A(kpf, sn);
    __builtin_amdgcn_sched_barrier(0);
    __builtin_amdgcn_s_barrier();
    asm volatile("s_waitcnt lgkmcnt(0)" ::: "memory");
    __builtin_amdgcn_sched_barrier(0);
    __builtin_amdgcn_s_setprio(1);
    mfma16(afr, bfr, acc, 0);
    __builtin_amdgcn_s_setprio(0);
    __builtin_amdgcn_sched_barrier(0);
    __builtin_amdgcn_s_barrier();

    // ---- phase 2: A frags mi4-7 (B reused), stage B-pair, 16 MFMA ----
    read_frag4(afr, As[s], wr * 128 + 64, l15, quad);
    if (pf) STAGE_B(kpf, sn);
    __builtin_amdgcn_sched_barrier(0);
    __builtin_amdgcn_s_barrier();
    asm volatile("s_waitcnt lgkmcnt(0)" ::: "memory");
    __builtin_amdgcn_sched_barrier(0);
    __builtin_amdgcn_s_setprio(1);
    mfma16(afr, bfr, acc, 4);
    __builtin_amdgcn_s_setprio(0);
    __builtin_amdgcn_sched_barrier(0);
    // counted drain: retire stage(t+1) before body t+1 reads slot t+1.
    if (pf)              { asm volatile("s_waitcnt vmcnt(8)" ::: "memory"); }
    else if (t + 2 < T)  { asm volatile("s_waitcnt vmcnt(4)" ::: "memory"); }
    else if (t + 1 < T)  { asm volatile("s_waitcnt vmcnt(0)" ::: "memory"); }
    __builtin_amdgcn_s_barrier();
  }
#undef STAGE_A
#undef STAGE_B

#pragma unroll
  for (int mi = 0; mi < 8; ++mi) {
    const int row = m0 + wr * 128 + mi * 16 + quad * 4;
#pragma unroll
    for (int ni = 0; ni < 4; ++ni) {
      const int col = n0 + wc * 64 + ni * 16 + l15;
#pragma unroll
      for (int r = 0; r < 4; ++r)
        C[(size_t)(row + r) * N + col] = acc[mi][ni][r];
    }
  }
}

// ---------------------------------------------------------------------------
// 128x128-tile GEMM (2-barrier structure). Used for the O-proj where the
// 256^2 grid would be only 128 blocks (half the chip idle); this one gives
// 512 blocks -> full occupancy, ~3 blocks/CU wave-level overlap.
#define BM 128
#define BN 128
#define BK 32

__global__ __launch_bounds__(256) void gemm_bt_kernel(
    const unsigned short* __restrict__ A,
    const unsigned short* __restrict__ B,
    float* __restrict__ C, int M, int N, int K) {
  __shared__ unsigned short As[BM * BK];
  __shared__ unsigned short Bs[BN * BK];
  const int m0 = blockIdx.y * BM;
  const int n0 = blockIdx.x * BN;
  const int tid = threadIdx.x;
  const int lane = tid & 63;
  const int l15 = lane & 15;
  const int quad = lane >> 4;
  const int w = tid >> 6;
  const int wm = (w >> 1) * 64;
  const int wn = (w & 1) * 64;

  floatx4 acc[4][4];
#pragma unroll
  for (int i = 0; i < 4; i++)
#pragma unroll
    for (int j = 0; j < 4; j++) acc[i][j] = (floatx4){0.f, 0.f, 0.f, 0.f};

  const int c0 = tid, c1 = tid + 256;
  const int r0 = c0 >> 2, o0 = (c0 & 3) * 8;
  const int r1 = c1 >> 2, o1 = (c1 & 3) * 8;

  for (int k0 = 0; k0 < K; k0 += BK) {
    __syncthreads();
    gload_lds16(A + (size_t)(m0 + r0) * K + k0 + o0, As + c0 * 8);
    gload_lds16(A + (size_t)(m0 + r1) * K + k0 + o1, As + c1 * 8);
    gload_lds16(B + (size_t)(n0 + r0) * K + k0 + o0, Bs + c0 * 8);
    gload_lds16(B + (size_t)(n0 + r1) * K + k0 + o1, Bs + c1 * 8);
    __syncthreads();

    bf16x8 a_frag[4], b_frag[4];
#pragma unroll
    for (int mt = 0; mt < 4; mt++)
      a_frag[mt] = *(const bf16x8*)&As[(wm + mt * 16 + l15) * BK + quad * 8];
#pragma unroll
    for (int nt = 0; nt < 4; nt++)
      b_frag[nt] = *(const bf16x8*)&Bs[(wn + nt * 16 + l15) * BK + quad * 8];
#pragma unroll
    for (int mt = 0; mt < 4; mt++)
#pragma unroll
      for (int nt = 0; nt < 4; nt++)
        acc[mt][nt] = __builtin_amdgcn_mfma_f32_16x16x32_bf16(
            a_frag[mt], b_frag[nt], acc[mt][nt], 0, 0, 0);
  }

#pragma unroll
  for (int mt = 0; mt < 4; mt++) {
#pragma unroll
    for (int nt = 0; nt < 4; nt++) {
      const int row = m0 + wm + mt * 16 + quad * 4;
      const int col = n0 + wn + nt * 16 + l15;
#pragma unroll
      for (int r = 0; r < 4; r++)
        C[(size_t)(row + r) * N + col] = acc[mt][nt][r];
    }
  }
}

// ---------------------------------------------------------------------------
__global__ void rope_kernel(const float* __restrict__ Cqkv,
                            const int* __restrict__ pos_ids,
                            unsigned short* __restrict__ Qb,
                            unsigned short* __restrict__ Kb) {
  int t = blockIdx.x * blockDim.x + threadIdx.x;  // s*64 + j
  int j = t & 63;
  int s = t >> 6;
  int hh = blockIdx.y;
  float pos = (float)pos_ids[s];
  float ang = pos * exp2f(-0.20762050593045222f * (float)j);
  float c = cosf(ang), sn = sinf(ang);
  if (hh < NH) {
    const float* row = Cqkv + (size_t)s * 6144 + hh * HD;
    float x1 = row[j], x2 = row[j + 64];
    unsigned short* q = Qb + ((size_t)hh * S_LEN + s) * HD;
    q[j]      = f2bf(x1 * c - x2 * sn);
    q[j + 64] = f2bf(x2 * c + x1 * sn);
  } else {
    int kh = hh - NH;
    const float* row = Cqkv + (size_t)s * 6144 + HID + kh * HD;
    float x1 = row[j], x2 = row[j + 64];
    unsigned short* k = Kb + ((size_t)kh * S_LEN + s) * HD;
    k[j]      = f2bf(x1 * c - x2 * sn);
    k[j + 64] = f2bf(x2 * c + x1 * sn);
  }
}

__global__ void vtrans_kernel(const float* __restrict__ Cqkv,
                              unsigned short* __restrict__ Vt) {
  int t = blockIdx.x * blockDim.x + threadIdx.x;
  int s = t & (S_LEN - 1);
  int d = (t >> 11) & (HD - 1);
  int kh = t >> 18;
  Vt[((size_t)kh * HD + d) * S_LEN + s] =
      f2bf(Cqkv[(size_t)s * 6144 + (HID + NKV * HD) + kh * HD + d]);
}

// ---------------------------------------------------------------------------
// Flash attention v4: double-buffered K/V LDS staging, ONE barrier per tile
// (stage kt+1 after barrier, compute kt -> DMA has full compute phase before
// its drain). Ps uses XOR chunk swizzle (no pad) so total LDS = 80 KB exactly
// -> 2 blocks/CU. No-max softmax; row sums via ones-column MFMA.
__global__ __launch_bounds__(256, 2) void flash_attn_kernel(
    const unsigned short* __restrict__ Qb, const unsigned short* __restrict__ Kb,
    const unsigned short* __restrict__ Vt, unsigned short* __restrict__ O) {
  __shared__ unsigned short Ks[2][64 * 128];     // 32 KB, chunk j ^ (row&15)
  __shared__ unsigned short Vs[2][128 * 64];     // 32 KB, chunk j ^ (d&7)
  __shared__ unsigned short Ps[4][2][16 * 64];   // 16 KB, chunk j ^ (row&7)
  const int qb = gridDim.x - 1 - blockIdx.x;     // heavy blocks dispatched first
  const int q0 = qb * 128;
  const int h = blockIdx.y;
  const int kvh = h >> 2;
  const int tid = threadIdx.x;
  const int lane = tid & 63;
  const int w = tid >> 6;
  const int l15 = lane & 15;
  const int quad = lane >> 4;
  const int qlo = q0 + w * 32;

  const unsigned short* Qh = Qb + (size_t)h * S_LEN * HD;
  const unsigned short* Kh = Kb + (size_t)kvh * S_LEN * HD;
  const unsigned short* Vh = Vt + (size_t)kvh * HD * S_LEN;

  const int nkt = q0 / 64 + 2;

  // prologue: stage tile 0 (overlaps Q-frag global loads)
#pragma unroll
  for (int it = 0; it < 4; it++) {
    int c = tid + it * 256;
    int kr = c >> 4, kj = (c & 15) ^ (kr & 15);
    gload_lds16(Kh + (size_t)kr * HD + kj * 8, Ks[0] + c * 8);
    int vd = c >> 3, vj = (c & 7) ^ (vd & 7);
    gload_lds16(Vh + (size_t)vd * S_LEN + vj * 8, Vs[0] + c * 8);
  }

  bf16x8 q_frag[2][4];
#pragma unroll
  for (int mf = 0; mf < 2; mf++)
#pragma unroll
    for (int kk = 0; kk < 4; kk++)
      q_frag[mf][kk] = *(const bf16x8*)&Qh[(size_t)(qlo + mf * 16 + l15) * HD + kk * 32 + quad * 8];

  // ones-column B fragment: B[n=0][k]=1 -> lanes with l15==0 hold 1.0
  bf16x8 ones_frag;
  {
    union { unsigned short u; __bf16 b; } ov;
    ov.u = (l15 == 0) ? 0x3F80 : 0;
#pragma unroll
    for (int j = 0; j < 8; j++) ones_frag[j] = ov.b;
  }

  floatx4 o_acc[2][8];
  floatx4 o_l[2];
#pragma unroll
  for (int mf = 0; mf < 2; mf++) {
#pragma unroll
    for (int i = 0; i < 8; i++) o_acc[mf][i] = (floatx4){0.f, 0.f, 0.f, 0.f};
    o_l[mf] = (floatx4){0.f, 0.f, 0.f, 0.f};
  }
  const float SC2 = 0.12751738f;  // (1/sqrt(128)) * log2(e)

  for (int kt = 0; kt < nkt; kt++) {
    const int kbase = kt * 64;
    const int buf = kt & 1;
    __syncthreads();  // buf staged (DMA drained); other buf's reads done

    if (kt + 1 < nkt) {  // stage NEXT tile into other buffer (drains next barrier)
      const int kb2 = kbase + 64;
#pragma unroll
      for (int it = 0; it < 4; it++) {
        int c = tid + it * 256;
        int kr = c >> 4, kj = (c & 15) ^ (kr & 15);
        gload_lds16(Kh + (size_t)(kb2 + kr) * HD + kj * 8, Ks[buf ^ 1] + c * 8);
        int vd = c >> 3, vj = (c & 7) ^ (vd & 7);
        gload_lds16(Vh + (size_t)vd * S_LEN + kb2 + vj * 8, Vs[buf ^ 1] + c * 8);
      }
    }

    if (kbase <= qlo + 31) {  // wave-uniform: skip fully-masked tiles
      floatx4 s_acc[2][4];
#pragma unroll
      for (int mf = 0; mf < 2; mf++)
#pragma unroll
        for (int nt = 0; nt < 4; nt++) s_acc[mf][nt] = (floatx4){0.f, 0.f, 0.f, 0.f};
#pragma unroll
      for (int kk = 0; kk < 4; kk++)
#pragma unroll
        for (int nt = 0; nt < 4; nt++) {
          bf16x8 k_frag = *(const bf16x8*)&Ks[buf][(nt * 16 + l15) * 128 + (((kk * 4 + quad) ^ l15) * 8)];
#pragma unroll
          for (int mf = 0; mf < 2; mf++)
            s_acc[mf][nt] = __builtin_amdgcn_mfma_f32_16x16x32_bf16(
                q_frag[mf][kk], k_frag, s_acc[mf][nt], 0, 0, 0);
        }

      // P = exp(s/sqrt(d)) (no max subtraction: |s| <~ 10), masked -> 0.
      // C-layout -> Ps (XOR chunk swizzle: chunk ^ (row&7)).
      const bool diag = (kbase + 63 > qlo);
#pragma unroll
      for (int mf = 0; mf < 2; mf++) {
#pragma unroll
        for (int nt = 0; nt < 4; nt++) {
          int kc = kbase + nt * 16 + l15;
          int qrow = qlo + mf * 16 + quad * 4;
          int chunk2 = nt * 2 + (l15 >> 3);
          int coff = l15 & 7;
#pragma unroll
          for (int r = 0; r < 4; r++) {
            float pv = exp2f(s_acc[mf][nt][r] * SC2);
            if (diag && kc > qrow + r) pv = 0.f;
            int row = quad * 4 + r;
            Ps[w][mf][row * 64 + ((chunk2 ^ (row & 7)) * 8) + coff] = f2bf(pv);
          }
        }
      }

      // PV + ones-column (row-sum) accumulation
#pragma unroll
      for (int kk2 = 0; kk2 < 2; kk2++) {
        bf16x8 p_frag[2];
#pragma unroll
        for (int mf = 0; mf < 2; mf++)
          p_frag[mf] = *(const bf16x8*)&Ps[w][mf][l15 * 64 + (((kk2 * 4 + quad) ^ (l15 & 7)) * 8)];
#pragma unroll
        for (int dt = 0; dt < 8; dt++) {
          bf16x8 v_frag = *(const bf16x8*)&Vs[buf][(dt * 16 + l15) * 64 + (((kk2 * 4 + quad) ^ (l15 & 7)) * 8)];
#pragma unroll
          for (int mf = 0; mf < 2; mf++)
            o_acc[mf][dt] = __builtin_amdgcn_mfma_f32_16x16x32_bf16(
                p_frag[mf], v_frag, o_acc[mf][dt], 0, 0, 0);
        }
#pragma unroll
        for (int mf = 0; mf < 2; mf++)
          o_l[mf] = __builtin_amdgcn_mfma_f32_16x16x32_bf16(
              p_frag[mf], ones_frag, o_l[mf], 0, 0, 0);
      }
    }
  }

#pragma unroll
  for (int mf = 0; mf < 2; mf++)
#pragma unroll
    for (int r = 0; r < 4; r++) {
      float lsum = __shfl(o_l[mf][r], lane & 48, 64);  // col 0 lives in l15==0
      float inv = 1.f / lsum;
      int qr = qlo + mf * 16 + quad * 4 + r;
#pragma unroll
      for (int dt = 0; dt < 8; dt++)
        O[(size_t)qr * HID + h * HD + dt * 16 + l15] = f2bf(o_acc[mf][dt][r] * inv);
    }
}

// ---------------------------------------------------------------------------
extern "C" void kernel_launch(void* const* d_in, const int* in_sizes, int n_in,
                              void* d_out, int out_size, void* d_ws, size_t ws_size,
                              hipStream_t stream) {
  const float* hidden = (const float*)d_in[0];
  const int*   pos    = (const int*)d_in[1];
  const float* Wq     = (const float*)d_in[2];
  const float* Wk     = (const float*)d_in[3];
  const float* Wv     = (const float*)d_in[4];
  const float* Wo     = (const float*)d_in[5];

  char* ws = (char*)d_ws;
  size_t off = 0;
  unsigned short* h_b    = (unsigned short*)(ws + off); off += (size_t)S_LEN * HID * 2;
  unsigned short* Wqkv_b = (unsigned short*)(ws + off); off += (size_t)6144 * HID * 2;
  unsigned short* Wo_b   = (unsigned short*)(ws + off); off += (size_t)HID * HID * 2;
  float*          Cqkv   = (float*)(ws + off);          off += (size_t)S_LEN * 6144 * 4;
  unsigned short* Qb     = (unsigned short*)(ws + off); off += (size_t)NH * S_LEN * HD * 2;
  unsigned short* Kb     = (unsigned short*)(ws + off); off += (size_t)NKV * S_LEN * HD * 2;
  unsigned short* Vt     = (unsigned short*)(ws + off); off += (size_t)NKV * HD * S_LEN * 2;
  unsigned short* attn_b = (unsigned short*)Cqkv;  // reuse (Cqkv dead after rope/vtrans)

  cast_bf16_kernel<<<(S_LEN * HID / 4) / 256, 256, 0, stream>>>(hidden, h_b, S_LEN * HID / 4);
  cast_bf16_kernel<<<(HID * HID / 4) / 256, 256, 0, stream>>>(Wq, Wqkv_b, HID * HID / 4);
  cast_bf16_kernel<<<(1024 * HID / 4) / 256, 256, 0, stream>>>(Wk, Wqkv_b + (size_t)4096 * HID, 1024 * HID / 4);
  cast_bf16_kernel<<<(1024 * HID / 4) / 256, 256, 0, stream>>>(Wv, Wqkv_b + (size_t)5120 * HID, 1024 * HID / 4);
  cast_bf16_kernel<<<(HID * HID / 4) / 256, 256, 0, stream>>>(Wo, Wo_b, HID * HID / 4);

  gemm_bt256_kernel<<<dim3(6144 / 256, S_LEN / 256), 512, 0, stream>>>(h_b, Wqkv_b, Cqkv, S_LEN, 6144, HID);

  rope_kernel<<<dim3(S_LEN * 64 / 256, NH + NKV), 256, 0, stream>>>(Cqkv, pos, Qb, Kb);
  vtrans_kernel<<<(NKV * HD * S_LEN) / 256, 256, 0, stream>>>(Cqkv, Vt);

  flash_attn_kernel<<<dim3(S_LEN / 128, NH), 256, 0, stream>>>(Qb, Kb, Vt, attn_b);

  gemm_bt_kernel<<<dim3(HID / BN, S_LEN / BM), 256, 0, stream>>>(attn_b, Wo_b, (float*)d_out, S_LEN, HID, HID);
}

// Round 6
// 546.861 us; speedup vs baseline: 1.0824x; 1.0824x over previous
//
#include <hip/hip_runtime.h>
#include <stdint.h>

// ---------------------------------------------------------------------------
// Llama GQA attention layer, MI355X/gfx950.
// Pipeline: cast->bf16, QKV gemm (256^2 v4 core), RoPE, V-transpose,
//           MFMA flash attention, O-proj gemm (256x128 v4 core, 256 blocks).
// v4 GEMM core: fragment double-buffer in registers, fine interleave
// ({reads | MFMA cluster} x4), ring-4 LDS K-tile slots, counted vmcnt
// (never 0 in steady state), ONE barrier per K-tile, conflict-free XOR
// swizzle f(row)=(row>>1)&3 (measured 0 bank conflicts).
// ---------------------------------------------------------------------------

typedef __attribute__((ext_vector_type(8))) __bf16 bf16x8;
typedef __attribute__((ext_vector_type(4))) float floatx4;

#define S_LEN 2048
#define HID   4096
#define NH    32
#define NKV   8
#define HD    128

__device__ __forceinline__ unsigned short f2bf(float f) {
  union { float f; uint32_t u; } v; v.f = f;
  return (unsigned short)((v.u + 0x7fffu + ((v.u >> 16) & 1u)) >> 16);
}

__device__ __forceinline__ void gload_lds16(const unsigned short* g, unsigned short* l) {
  __builtin_amdgcn_global_load_lds(
      (const __attribute__((address_space(1))) void*)g,
      (__attribute__((address_space(3))) void*)l,
      16, 0, 0);
}

// ---------------------------------------------------------------------------
__global__ void cast_bf16_kernel(const float* __restrict__ in,
                                 unsigned short* __restrict__ out, int n4) {
  int i = blockIdx.x * blockDim.x + threadIdx.x;
  if (i >= n4) return;
  float4 f = ((const float4*)in)[i];
  ushort4 o = make_ushort4(f2bf(f.x), f2bf(f.y), f2bf(f.z), f2bf(f.w));
  ((ushort4*)out)[i] = o;
}

// ---------------------------------------------------------------------------
#define GT 32   // K per LDS tile

__device__ __forceinline__ void read_frag4(
    bf16x8* f, const unsigned short* S, int row0, int l15, int quad) {
#pragma unroll
  for (int i = 0; i < 4; ++i) {
    const int row = row0 + i * 16 + l15;
    f[i] = *(const bf16x8*)&S[row * GT + (((quad ^ (row >> 1)) & 3) * 8)];
  }
}

__device__ __forceinline__ void mfma_c8(
    const bf16x8* a, const bf16x8* b, floatx4 acc[8][4], int mi0) {
#pragma unroll
  for (int mi = 0; mi < 2; ++mi)
#pragma unroll
    for (int ni = 0; ni < 4; ++ni)
      acc[mi0 + mi][ni] = __builtin_amdgcn_mfma_f32_16x16x32_bf16(
          a[mi], b[ni], acc[mi0 + mi][ni], 0, 0, 0);
}

__device__ __forceinline__ void mfma8_44(
    const bf16x8* a, const bf16x8* b, floatx4 acc[4][4], int mi0) {
#pragma unroll
  for (int mi = 0; mi < 2; ++mi)
#pragma unroll
    for (int ni = 0; ni < 4; ++ni)
      acc[mi0 + mi][ni] = __builtin_amdgcn_mfma_f32_16x16x32_bf16(
          a[mi], b[ni], acc[mi0 + mi][ni], 0, 0, 0);
}

// ---------------------------------------------------------------------------
// 256x256-tile GEMM (v4, round-4 verified 132 us / 781 TF on QKV shape).
// 512 threads (8 waves = 2M x 4N), wave tile 128x64, BK=32.
// Body t: {read NXT A0-3 | 8 MFMA} {read NXT A4-7 | 8 MFMA}
//         {read NXT B0-3 | 8 MFMA} {stage t+3 | 8 MFMA} lgkm0 vmcnt barrier.
__global__ __launch_bounds__(512, 2) void gemm_bt256_kernel(
    const unsigned short* __restrict__ A,
    const unsigned short* __restrict__ B,
    float* __restrict__ C, int M, int N, int K) {
  __shared__ unsigned short As[4][256 * GT];   // 64 KB
  __shared__ unsigned short Bs[4][256 * GT];   // 64 KB
  const int m0 = blockIdx.y * 256;
  const int n0 = blockIdx.x * 256;
  const int tid = threadIdx.x;
  const int lane = tid & 63;
  const int wv = tid >> 6;
  const int wr = wv >> 2;
  const int wc = wv & 3;
  const int l15 = lane & 15;
  const int quad = lane >> 4;

  const int ch0 = wv * 64 + lane;
  const int ch1 = ch0 + 512;
  const int cs0 = ch0 ^ ((ch0 >> 3) & 3);
  const int cs1 = ch1 ^ ((ch1 >> 3) & 3);
  const int r0s = cs0 >> 2, c0s = (cs0 & 3) * 8;
  const int r1s = cs1 >> 2, c1s = (cs1 & 3) * 8;

  floatx4 acc[8][4];
#pragma unroll
  for (int i = 0; i < 8; i++)
#pragma unroll
    for (int j = 0; j < 4; j++) acc[i][j] = (floatx4){0.f, 0.f, 0.f, 0.f};

  const int T = K / GT;

#define STAGE_T(kk0, s)                                                        \
  do {                                                                         \
    gload_lds16(A + (size_t)(m0 + r0s) * K + (kk0) + c0s, &As[s][ch0 * 8]);    \
    gload_lds16(A + (size_t)(m0 + r1s) * K + (kk0) + c1s, &As[s][ch1 * 8]);    \
    gload_lds16(B + (size_t)(n0 + r0s) * K + (kk0) + c0s, &Bs[s][ch0 * 8]);    \
    gload_lds16(B + (size_t)(n0 + r1s) * K + (kk0) + c1s, &Bs[s][ch1 * 8]);    \
  } while (0)

  STAGE_T(0, 0);
  STAGE_T(GT, 1);
  STAGE_T(2 * GT, 2);
  asm volatile("s_waitcnt vmcnt(4)" ::: "memory");
  __builtin_amdgcn_s_barrier();

  bf16x8 fA[12], fB[12];
  read_frag4(fA + 0, As[0], wr * 128, l15, quad);
  read_frag4(fA + 4, As[0], wr * 128 + 64, l15, quad);
  read_frag4(fA + 8, Bs[0], wc * 64, l15, quad);
  asm volatile("s_waitcnt lgkmcnt(0)" ::: "memory");
  __builtin_amdgcn_sched_barrier(0);

#define MCLUSTER(CUR, mi0)                                                     \
  __builtin_amdgcn_sched_barrier(0);                                           \
  __builtin_amdgcn_s_setprio(1);                                               \
  mfma_c8((CUR) + (mi0), (CUR) + 8, acc, (mi0));                               \
  __builtin_amdgcn_s_setprio(0);                                               \
  __builtin_amdgcn_sched_barrier(0);

#define BODY(tt, CUR, NXT)                                                     \
  do {                                                                         \
    const int t_ = (tt);                                                       \
    const int sl_ = (t_ + 1) & 3;                                              \
    const bool rd_ = (t_ + 1 < T);                                             \
    if (rd_) read_frag4((NXT) + 0, As[sl_], wr * 128, l15, quad);              \
    MCLUSTER(CUR, 0)                                                           \
    if (rd_) read_frag4((NXT) + 4, As[sl_], wr * 128 + 64, l15, quad);         \
    MCLUSTER(CUR, 2)                                                           \
    if (rd_) read_frag4((NXT) + 8, Bs[sl_], wc * 64, l15, quad);               \
    MCLUSTER(CUR, 4)                                                           \
    if (t_ + 3 < T) STAGE_T((t_ + 3) * GT, (t_ + 3) & 3);                      \
    MCLUSTER(CUR, 6)                                                           \
    asm volatile("s_waitcnt lgkmcnt(0)" ::: "memory");                         \
    if (t_ + 3 < T)      { asm volatile("s_waitcnt vmcnt(4)" ::: "memory"); }  \
    else if (t_ + 2 < T) { asm volatile("s_waitcnt vmcnt(0)" ::: "memory"); }  \
    __builtin_amdgcn_sched_barrier(0);                                         \
    __builtin_amdgcn_s_barrier();                                              \
  } while (0)

  for (int t = 0; t < T; t += 2) {
    BODY(t, fA, fB);
    BODY(t + 1, fB, fA);
  }
#undef BODY
#undef MCLUSTER
#undef STAGE_T

#pragma unroll
  for (int mi = 0; mi < 8; ++mi) {
    const int row = m0 + wr * 128 + mi * 16 + quad * 4;
#pragma unroll
    for (int ni = 0; ni < 4; ++ni) {
      const int col = n0 + wc * 64 + ni * 16 + l15;
#pragma unroll
      for (int r = 0; r < 4; ++r)
        C[(size_t)(row + r) * N + col] = acc[mi][ni][r];
    }
  }
}

// ---------------------------------------------------------------------------
// 256x128-tile GEMM (v4 core, sized so the O-proj grid is exactly 256 blocks
// = one per CU, full fill). 512 threads (8 waves = 4M x 2N), wave tile 64x64.
// LDS: ring-4 of (A 256x32 = 16KB) + (B 128x32 = 8KB) = 96 KB -> 1 block/CU.
// Staging: A = 1024 chunks (2/thread), B = 512 chunks (1/thread) -> 3 gloads
// per thread per tile. Prologue stages tiles 0,1,2 (9 loads); vmcnt(3)
// retires tiles 0+1. Steady-state vmcnt(3) retires stage(t+1) at end of body
// t before body t+1 reads slot t+1. Same swizzle/race analysis as 256^2.
__global__ __launch_bounds__(512, 2) void gemm_bt_256x128_kernel(
    const unsigned short* __restrict__ A,
    const unsigned short* __restrict__ B,
    float* __restrict__ C, int M, int N, int K) {
  __shared__ unsigned short As[4][256 * GT];   // 64 KB
  __shared__ unsigned short Bs[4][128 * GT];   // 32 KB
  const int m0 = blockIdx.y * 256;
  const int n0 = blockIdx.x * 128;
  const int tid = threadIdx.x;
  const int lane = tid & 63;
  const int wv = tid >> 6;
  const int wr = wv >> 1;         // 0..3 -> rows [wr*64, +64)
  const int wc = wv & 1;          // 0..1 -> cols [wc*64, +64)
  const int l15 = lane & 15;
  const int quad = lane >> 4;

  // A staging (1024 chunks, 2/thread); B staging (512 chunks, 1/thread).
  const int ch0 = wv * 64 + lane;
  const int ch1 = ch0 + 512;
  const int cs0 = ch0 ^ ((ch0 >> 3) & 3);
  const int cs1 = ch1 ^ ((ch1 >> 3) & 3);
  const int r0s = cs0 >> 2, c0s = (cs0 & 3) * 8;
  const int r1s = cs1 >> 2, c1s = (cs1 & 3) * 8;
  const int chb = tid;
  const int csb = chb ^ ((chb >> 3) & 3);
  const int rbs = csb >> 2, cbs = (csb & 3) * 8;   // row 0..127

  floatx4 acc[4][4];
#pragma unroll
  for (int i = 0; i < 4; i++)
#pragma unroll
    for (int j = 0; j < 4; j++) acc[i][j] = (floatx4){0.f, 0.f, 0.f, 0.f};

  const int T = K / GT;

#define STAGE_T(kk0, s)                                                        \
  do {                                                                         \
    gload_lds16(A + (size_t)(m0 + r0s) * K + (kk0) + c0s, &As[s][ch0 * 8]);    \
    gload_lds16(A + (size_t)(m0 + r1s) * K + (kk0) + c1s, &As[s][ch1 * 8]);    \
    gload_lds16(B + (size_t)(n0 + rbs) * K + (kk0) + cbs, &Bs[s][chb * 8]);    \
  } while (0)

  STAGE_T(0, 0);
  STAGE_T(GT, 1);
  STAGE_T(2 * GT, 2);
  asm volatile("s_waitcnt vmcnt(3)" ::: "memory");
  __builtin_amdgcn_s_barrier();

  // frag layout: f[0..3] = A frags, f[4..7] = B frags
  bf16x8 fA[8], fB[8];
  read_frag4(fA + 0, As[0], wr * 64, l15, quad);
  read_frag4(fA + 4, Bs[0], wc * 64, l15, quad);
  asm volatile("s_waitcnt lgkmcnt(0)" ::: "memory");
  __builtin_amdgcn_sched_barrier(0);

#define MC8(CUR, mi0)                                                          \
  __builtin_amdgcn_sched_barrier(0);                                           \
  __builtin_amdgcn_s_setprio(1);                                               \
  mfma8_44((CUR) + (mi0), (CUR) + 4, acc, (mi0));                              \
  __builtin_amdgcn_s_setprio(0);                                               \
  __builtin_amdgcn_sched_barrier(0);

#define BODY(tt, CUR, NXT)                                                     \
  do {                                                                         \
    const int t_ = (tt);                                                       \
    const int sl_ = (t_ + 1) & 3;                                              \
    const bool rd_ = (t_ + 1 < T);                                             \
    if (rd_) read_frag4((NXT) + 0, As[sl_], wr * 64, l15, quad);               \
    MC8(CUR, 0)                                                                \
    if (rd_) read_frag4((NXT) + 4, Bs[sl_], wc * 64, l15, quad);               \
    if (t_ + 3 < T) STAGE_T((t_ + 3) * GT, (t_ + 3) & 3);                      \
    MC8(CUR, 2)                                                                \
    asm volatile("s_waitcnt lgkmcnt(0)" ::: "memory");                         \
    if (t_ + 3 < T)      { asm volatile("s_waitcnt vmcnt(3)" ::: "memory"); }  \
    else if (t_ + 2 < T) { asm volatile("s_waitcnt vmcnt(0)" ::: "memory"); }  \
    __builtin_amdgcn_sched_barrier(0);                                         \
    __builtin_amdgcn_s_barrier();                                              \
  } while (0)

  for (int t = 0; t < T; t += 2) {
    BODY(t, fA, fB);
    BODY(t + 1, fB, fA);
  }
#undef BODY
#undef MC8
#undef STAGE_T

#pragma unroll
  for (int mi = 0; mi < 4; ++mi) {
    const int row = m0 + wr * 64 + mi * 16 + quad * 4;
#pragma unroll
    for (int ni = 0; ni < 4; ++ni) {
      const int col = n0 + wc * 64 + ni * 16 + l15;
#pragma unroll
      for (int r = 0; r < 4; ++r)
        C[(size_t)(row + r) * N + col] = acc[mi][ni][r];
    }
  }
}

// ---------------------------------------------------------------------------
__global__ void rope_kernel(const float* __restrict__ Cqkv,
                            const int* __restrict__ pos_ids,
                            unsigned short* __restrict__ Qb,
                            unsigned short* __restrict__ Kb) {
  int t = blockIdx.x * blockDim.x + threadIdx.x;  // s*64 + j
  int j = t & 63;
  int s = t >> 6;
  int hh = blockIdx.y;
  float pos = (float)pos_ids[s];
  float ang = pos * exp2f(-0.20762050593045222f * (float)j);
  float c = cosf(ang), sn = sinf(ang);
  if (hh < NH) {
    const float* row = Cqkv + (size_t)s * 6144 + hh * HD;
    float x1 = row[j], x2 = row[j + 64];
    unsigned short* q = Qb + ((size_t)hh * S_LEN + s) * HD;
    q[j]      = f2bf(x1 * c - x2 * sn);
    q[j + 64] = f2bf(x2 * c + x1 * sn);
  } else {
    int kh = hh - NH;
    const float* row = Cqkv + (size_t)s * 6144 + HID + kh * HD;
    float x1 = row[j], x2 = row[j + 64];
    unsigned short* k = Kb + ((size_t)kh * S_LEN + s) * HD;
    k[j]      = f2bf(x1 * c - x2 * sn);
    k[j + 64] = f2bf(x2 * c + x1 * sn);
  }
}

__global__ void vtrans_kernel(const float* __restrict__ Cqkv,
                              unsigned short* __restrict__ Vt) {
  int t = blockIdx.x * blockDim.x + threadIdx.x;
  int s = t & (S_LEN - 1);
  int d = (t >> 11) & (HD - 1);
  int kh = t >> 18;
  Vt[((size_t)kh * HD + d) * S_LEN + s] =
      f2bf(Cqkv[(size_t)s * 6144 + (HID + NKV * HD) + kh * HD + d]);
}

// ---------------------------------------------------------------------------
// Flash attention v4: double-buffered K/V LDS staging, ONE barrier per tile
// (stage kt+1 after barrier, compute kt -> DMA has full compute phase before
// its drain). Ps uses XOR chunk swizzle (no pad) so total LDS = 80 KB exactly
// -> 2 blocks/CU. No-max softmax; row sums via ones-column MFMA.
__global__ __launch_bounds__(256, 2) void flash_attn_kernel(
    const unsigned short* __restrict__ Qb, const unsigned short* __restrict__ Kb,
    const unsigned short* __restrict__ Vt, unsigned short* __restrict__ O) {
  __shared__ unsigned short Ks[2][64 * 128];     // 32 KB, chunk j ^ (row&15)
  __shared__ unsigned short Vs[2][128 * 64];     // 32 KB, chunk j ^ (d&7)
  __shared__ unsigned short Ps[4][2][16 * 64];   // 16 KB, chunk j ^ (row&7)
  const int qb = gridDim.x - 1 - blockIdx.x;     // heavy blocks dispatched first
  const int q0 = qb * 128;
  const int h = blockIdx.y;
  const int kvh = h >> 2;
  const int tid = threadIdx.x;
  const int lane = tid & 63;
  const int w = tid >> 6;
  const int l15 = lane & 15;
  const int quad = lane >> 4;
  const int qlo = q0 + w * 32;

  const unsigned short* Qh = Qb + (size_t)h * S_LEN * HD;
  const unsigned short* Kh = Kb + (size_t)kvh * S_LEN * HD;
  const unsigned short* Vh = Vt + (size_t)kvh * HD * S_LEN;

  const int nkt = q0 / 64 + 2;

  // prologue: stage tile 0 (overlaps Q-frag global loads)
#pragma unroll
  for (int it = 0; it < 4; it++) {
    int c = tid + it * 256;
    int kr = c >> 4, kj = (c & 15) ^ (kr & 15);
    gload_lds16(Kh + (size_t)kr * HD + kj * 8, Ks[0] + c * 8);
    int vd = c >> 3, vj = (c & 7) ^ (vd & 7);
    gload_lds16(Vh + (size_t)vd * S_LEN + vj * 8, Vs[0] + c * 8);
  }

  bf16x8 q_frag[2][4];
#pragma unroll
  for (int mf = 0; mf < 2; mf++)
#pragma unroll
    for (int kk = 0; kk < 4; kk++)
      q_frag[mf][kk] = *(const bf16x8*)&Qh[(size_t)(qlo + mf * 16 + l15) * HD + kk * 32 + quad * 8];

  // ones-column B fragment: B[n=0][k]=1 -> lanes with l15==0 hold 1.0
  bf16x8 ones_frag;
  {
    union { unsigned short u; __bf16 b; } ov;
    ov.u = (l15 == 0) ? 0x3F80 : 0;
#pragma unroll
    for (int j = 0; j < 8; j++) ones_frag[j] = ov.b;
  }

  floatx4 o_acc[2][8];
  floatx4 o_l[2];
#pragma unroll
  for (int mf = 0; mf < 2; mf++) {
#pragma unroll
    for (int i = 0; i < 8; i++) o_acc[mf][i] = (floatx4){0.f, 0.f, 0.f, 0.f};
    o_l[mf] = (floatx4){0.f, 0.f, 0.f, 0.f};
  }
  const float SC2 = 0.12751738f;  // (1/sqrt(128)) * log2(e)

  for (int kt = 0; kt < nkt; kt++) {
    const int kbase = kt * 64;
    const int buf = kt & 1;
    __syncthreads();  // buf staged (DMA drained); other buf's reads done

    if (kt + 1 < nkt) {  // stage NEXT tile into other buffer (drains next barrier)
      const int kb2 = kbase + 64;
#pragma unroll
      for (int it = 0; it < 4; it++) {
        int c = tid + it * 256;
        int kr = c >> 4, kj = (c & 15) ^ (kr & 15);
        gload_lds16(Kh + (size_t)(kb2 + kr) * HD + kj * 8, Ks[buf ^ 1] + c * 8);
        int vd = c >> 3, vj = (c & 7) ^ (vd & 7);
        gload_lds16(Vh + (size_t)vd * S_LEN + kb2 + vj * 8, Vs[buf ^ 1] + c * 8);
      }
    }

    if (kbase <= qlo + 31) {  // wave-uniform: skip fully-masked tiles
      floatx4 s_acc[2][4];
#pragma unroll
      for (int mf = 0; mf < 2; mf++)
#pragma unroll
        for (int nt = 0; nt < 4; nt++) s_acc[mf][nt] = (floatx4){0.f, 0.f, 0.f, 0.f};
#pragma unroll
      for (int kk = 0; kk < 4; kk++)
#pragma unroll
        for (int nt = 0; nt < 4; nt++) {
          bf16x8 k_frag = *(const bf16x8*)&Ks[buf][(nt * 16 + l15) * 128 + (((kk * 4 + quad) ^ l15) * 8)];
#pragma unroll
          for (int mf = 0; mf < 2; mf++)
            s_acc[mf][nt] = __builtin_amdgcn_mfma_f32_16x16x32_bf16(
                q_frag[mf][kk], k_frag, s_acc[mf][nt], 0, 0, 0);
        }

      // P = exp(s/sqrt(d)) (no max subtraction: |s| <~ 10), masked -> 0.
      // C-layout -> Ps (XOR chunk swizzle: chunk ^ (row&7)).
      const bool diag = (kbase + 63 > qlo);
#pragma unroll
      for (int mf = 0; mf < 2; mf++) {
#pragma unroll
        for (int nt = 0; nt < 4; nt++) {
          int kc = kbase + nt * 16 + l15;
          int qrow = qlo + mf * 16 + quad * 4;
          int chunk2 = nt * 2 + (l15 >> 3);
          int coff = l15 & 7;
#pragma unroll
          for (int r = 0; r < 4; r++) {
            float pv = exp2f(s_acc[mf][nt][r] * SC2);
            if (diag && kc > qrow + r) pv = 0.f;
            int row = quad * 4 + r;
            Ps[w][mf][row * 64 + ((chunk2 ^ (row & 7)) * 8) + coff] = f2bf(pv);
          }
        }
      }

      // PV + ones-column (row-sum) accumulation
#pragma unroll
      for (int kk2 = 0; kk2 < 2; kk2++) {
        bf16x8 p_frag[2];
#pragma unroll
        for (int mf = 0; mf < 2; mf++)
          p_frag[mf] = *(const bf16x8*)&Ps[w][mf][l15 * 64 + (((kk2 * 4 + quad) ^ (l15 & 7)) * 8)];
#pragma unroll
        for (int dt = 0; dt < 8; dt++) {
          bf16x8 v_frag = *(const bf16x8*)&Vs[buf][(dt * 16 + l15) * 64 + (((kk2 * 4 + quad) ^ (l15 & 7)) * 8)];
#pragma unroll
          for (int mf = 0; mf < 2; mf++)
            o_acc[mf][dt] = __builtin_amdgcn_mfma_f32_16x16x32_bf16(
                p_frag[mf], v_frag, o_acc[mf][dt], 0, 0, 0);
        }
#pragma unroll
        for (int mf = 0; mf < 2; mf++)
          o_l[mf] = __builtin_amdgcn_mfma_f32_16x16x32_bf16(
              p_frag[mf], ones_frag, o_l[mf], 0, 0, 0);
      }
    }
  }

#pragma unroll
  for (int mf = 0; mf < 2; mf++)
#pragma unroll
    for (int r = 0; r < 4; r++) {
      float lsum = __shfl(o_l[mf][r], lane & 48, 64);  // col 0 lives in l15==0
      float inv = 1.f / lsum;
      int qr = qlo + mf * 16 + quad * 4 + r;
#pragma unroll
      for (int dt = 0; dt < 8; dt++)
        O[(size_t)qr * HID + h * HD + dt * 16 + l15] = f2bf(o_acc[mf][dt][r] * inv);
    }
}

// ---------------------------------------------------------------------------
extern "C" void kernel_launch(void* const* d_in, const int* in_sizes, int n_in,
                              void* d_out, int out_size, void* d_ws, size_t ws_size,
                              hipStream_t stream) {
  const float* hidden = (const float*)d_in[0];
  const int*   pos    = (const int*)d_in[1];
  const float* Wq     = (const float*)d_in[2];
  const float* Wk     = (const float*)d_in[3];
  const float* Wv     = (const float*)d_in[4];
  const float* Wo     = (const float*)d_in[5];

  char* ws = (char*)d_ws;
  size_t off = 0;
  unsigned short* h_b    = (unsigned short*)(ws + off); off += (size_t)S_LEN * HID * 2;
  unsigned short* Wqkv_b = (unsigned short*)(ws + off); off += (size_t)6144 * HID * 2;
  unsigned short* Wo_b   = (unsigned short*)(ws + off); off += (size_t)HID * HID * 2;
  float*          Cqkv   = (float*)(ws + off);          off += (size_t)S_LEN * 6144 * 4;
  unsigned short* Qb     = (unsigned short*)(ws + off); off += (size_t)NH * S_LEN * HD * 2;
  unsigned short* Kb     = (unsigned short*)(ws + off); off += (size_t)NKV * S_LEN * HD * 2;
  unsigned short* Vt     = (unsigned short*)(ws + off); off += (size_t)NKV * HD * S_LEN * 2;
  unsigned short* attn_b = (unsigned short*)Cqkv;  // reuse (Cqkv dead after rope/vtrans)

  cast_bf16_kernel<<<(S_LEN * HID / 4) / 256, 256, 0, stream>>>(hidden, h_b, S_LEN * HID / 4);
  cast_bf16_kernel<<<(HID * HID / 4) / 256, 256, 0, stream>>>(Wq, Wqkv_b, HID * HID / 4);
  cast_bf16_kernel<<<(1024 * HID / 4) / 256, 256, 0, stream>>>(Wk, Wqkv_b + (size_t)4096 * HID, 1024 * HID / 4);
  cast_bf16_kernel<<<(1024 * HID / 4) / 256, 256, 0, stream>>>(Wv, Wqkv_b + (size_t)5120 * HID, 1024 * HID / 4);
  cast_bf16_kernel<<<(HID * HID / 4) / 256, 256, 0, stream>>>(Wo, Wo_b, HID * HID / 4);

  gemm_bt256_kernel<<<dim3(6144 / 256, S_LEN / 256), 512, 0, stream>>>(h_b, Wqkv_b, Cqkv, S_LEN, 6144, HID);

  rope_kernel<<<dim3(S_LEN * 64 / 256, NH + NKV), 256, 0, stream>>>(Cqkv, pos, Qb, Kb);
  vtrans_kernel<<<(NKV * HD * S_LEN) / 256, 256, 0, stream>>>(Cqkv, Vt);

  flash_attn_kernel<<<dim3(S_LEN / 128, NH), 256, 0, stream>>>(Qb, Kb, Vt, attn_b);

  gemm_bt_256x128_kernel<<<dim3(HID / 128, S_LEN / 256), 512, 0, stream>>>(attn_b, Wo_b, (float*)d_out, S_LEN, HID, HID);
}